// Round 10
// baseline (323.302 us; speedup 1.0000x reference)
//
#include <hip/hip_runtime.h>
#include <hip/hip_bf16.h>

#define BB 4
#define HH 256
#define LL 8192
#define NN 32
#define CH 64      // chunks per (b,h)
#define TT 128     // chunk length; CH*TT == LL

typedef __attribute__((ext_vector_type(4))) float f32x4;
typedef __attribute__((ext_vector_type(8))) short s16x8;
typedef __attribute__((ext_vector_type(4))) short s16x4;
typedef unsigned int u32;

static __device__ __forceinline__ ushort f2bf(float f){
    union { float f; unsigned int i; } v; v.f = f;
    unsigned int x = v.i;
    return (ushort)((x + 0x7fffu + ((x >> 16) & 1u)) >> 16);   // RNE
}

// branch-free GELU (tanh form, native exp2/rcp). |err| <~1e-3 abs, << bf16 path noise.
static __device__ __forceinline__ float fast_gelu(float x){
    float x3 = x*x*x;
    float z  = fmaf(0.03567740814f, x3, 0.7978845608f*x);
    float e  = __builtin_amdgcn_exp2f(z * 2.885390082f);       // exp(2z)
    float t  = 1.f - 2.f*__builtin_amdgcn_rcpf(e + 1.f);       // tanh(z)
    return 0.5f*x*(1.f + t);
}
static __device__ __forceinline__ float fast_sigmoid(float x){
    float e = __builtin_amdgcn_exp2f(-x * 1.442695041f);       // exp(-x)
    return __builtin_amdgcn_rcpf(1.f + e);
}

// ---------------- weight conversion fp32 -> bf16 ----------------
__global__ void k_prep_weights(const float* __restrict__ gw, const float* __restrict__ fiw,
                               const float* __restrict__ fow,
                               ushort* __restrict__ dglu, ushort* __restrict__ dfi,
                               ushort* __restrict__ dfo){
    int i = blockIdx.x * 256 + threadIdx.x;           // grid covers 262144
    if (i < 512*256)  dglu[i] = f2bf(gw[i]);
    if (i < 1024*256) dfi[i]  = f2bf(fiw[i]);
    if (i < 1024*256) dfo[i]  = f2bf(fow[i]);
}

// ---------------- scan parameters: w, w^T per (h,n) ----------------
__global__ void k_scan_params(const float* __restrict__ log_dt, const float* __restrict__ log_A_real,
                              const float* __restrict__ A_imag, float4* __restrict__ out){
    int i = blockIdx.x * 256 + threadIdx.x;           // < H*N = 8192
    int h = i >> 5;
    float dt  = expf(log_dt[h]);
    float Are = -expf(log_A_real[i]);
    float Aim = A_imag[i];
    float xr = Are * dt, xi = Aim * dt;               // dtA
    float er = expf(xr), sn, cs;
    sincosf(xi, &sn, &cs);
    float erT = expf(xr * (float)TT), snT, csT;
    sincosf(xi * (float)TT, &snT, &csT);
    out[i] = make_float4(er*cs, er*sn, erT*csT, erT*snT);   // w, w^T
}

// ---------------- build per-h GEMM operands: Toeplitz Tk, carry M2, end-state V2 ----------------
__global__ void __launch_bounds__(256) k_build(const float* __restrict__ log_dt,
      const float* __restrict__ log_A_real, const float* __restrict__ A_imag,
      const float* __restrict__ C_re, const float* __restrict__ C_im, const float* __restrict__ Dp,
      ushort* __restrict__ Tkb, ushort* __restrict__ M2b, ushort* __restrict__ V2b){
    int h = blockIdx.x, tid = threadIdx.x;
    __shared__ float prm[4][32];            // xr, xi, ccre, ccim
    __shared__ float2 pw[129][32];          // w^d
    __shared__ float kk[129];               // real kernel k[d]
    if (tid < 32){
        int n = tid, i = h*NN + n;
        float dt  = expf(log_dt[h]);
        float Are = -expf(log_A_real[i]);
        float Aim = A_imag[i];
        float xr = Are*dt, xi = Aim*dt;
        float er = expf(xr), sn, cs; sincosf(xi, &sn, &cs);
        float wre = er*cs, wim = er*sn;
        float nre = wre - 1.f, nim = wim;
        float inv = 1.f / (Are*Are + Aim*Aim);
        float qre = (nre*Are + nim*Aim) * inv;
        float qim = (nim*Are - nre*Aim) * inv;
        float cre = C_re[i], cim = C_im[i];
        prm[0][n] = xr; prm[1][n] = xi;
        prm[2][n] = 2.f*(cre*qre - cim*qim);      // ccre (2*Cc)
        prm[3][n] = 2.f*(cre*qim + cim*qre);      // ccim
    }
    __syncthreads();
    if (tid < 129){
        float d = (float)tid, acc = 0.f;
        for (int n = 0; n < 32; ++n){
            float er = expf(prm[0][n]*d), sn, cs; sincosf(prm[1][n]*d, &sn, &cs);
            float pre = er*cs, pim = er*sn;
            pw[tid][n] = make_float2(pre, pim);
            acc += prm[2][n]*pre - prm[3][n]*pim;
        }
        kk[tid] = acc;
    }
    __syncthreads();
    float k0d = kk[0] + Dp[h];
    for (int idx = tid; idx < 128*128; idx += 256){       // Tk[t][tau]
        int t = idx >> 7, ta = idx & 127, d = t - ta;
        float v = (d < 0) ? 0.f : ((d == 0) ? k0d : kk[d]);
        Tkb[(size_t)h*16384 + idx] = f2bf(v);
    }
    for (int idx = tid; idx < 128*64; idx += 256){        // M2[t][0:32]=Re(cc w^{t+1}); [32:64]=-Im
        int t = idx >> 6, j = idx & 63, n = j & 31;
        float2 p = pw[t+1][n];
        float v = (j < 32) ?  (prm[2][n]*p.x - prm[3][n]*p.y)
                           : -(prm[2][n]*p.y + prm[3][n]*p.x);
        M2b[(size_t)h*8192 + idx] = f2bf(v);
    }
    for (int idx = tid; idx < 64*128; idx += 256){        // V2[row][tau] = re/im of w^{127-tau}
        int row = idx >> 7, ta = idx & 127, n = row & 31;
        float2 p = pw[127 - ta][n];
        V2b[(size_t)h*8192 + idx] = f2bf(row < 32 ? p.x : p.y);
    }
}

// ---------------- channel LayerNorm (over H at each (b,l)) ----------------
// MODE 1: bf16 out, transposed (B,L,H). MODE 2: bf16 out, (B,H,L).
template<int MODE>
__global__ void __launch_bounds__(256) k_ln(const float* __restrict__ in, void* __restrict__ outp,
                     const float* __restrict__ gamma, const float* __restrict__ beta){
    int p = threadIdx.x & 63, cg = threadIdx.x >> 6;
    int b  = blockIdx.x / (LL/64);
    int l  = (blockIdx.x % (LL/64)) * 64 + p;
    const float* base = in + (size_t)b*HH*LL + l;
    int c0 = cg * 64;
    float s = 0.f, s2 = 0.f;
    #pragma unroll 8
    for (int j = 0; j < 64; ++j){
        float v = base[(size_t)(c0+j)*LL];
        s += v; s2 += v*v;
    }
    __shared__ float red[2][4][64];
    red[0][cg][p] = s; red[1][cg][p] = s2;
    __syncthreads();
    float ts = red[0][0][p]+red[0][1][p]+red[0][2][p]+red[0][3][p];
    float tq = red[1][0][p]+red[1][1][p]+red[1][2][p]+red[1][3][p];
    float mu   = ts * (1.f/HH);
    float var  = tq * (1.f/HH) - mu*mu;
    float rstd = rsqrtf(var + 1e-5f);
    if (MODE == 1){
        ushort* ob = (ushort*)outp + ((size_t)(b*LL + l))*HH + c0;
        #pragma unroll
        for (int j8 = 0; j8 < 8; ++j8){
            s16x8 v;
            #pragma unroll
            for (int e = 0; e < 8; ++e){
                int c = c0 + j8*8 + e;
                v[e] = (short)f2bf((base[(size_t)c*LL] - mu)*rstd*gamma[c] + beta[c]);
            }
            *(s16x8*)(ob + j8*8) = v;
        }
    } else {
        ushort* ob = (ushort*)outp + (size_t)b*HH*LL + l;
        #pragma unroll 8
        for (int j = 0; j < 64; ++j){
            int c = c0 + j;
            ob[(size_t)c*LL] = f2bf((base[(size_t)c*LL] - mu)*rstd*gamma[c] + beta[c]);
        }
    }
}

// ---------------- scan pass A (GEMM): E[64 x CH] = V2_h @ U ----------------
__global__ void __launch_bounds__(256) k_gemmA(const ushort* __restrict__ V2b,
                        const ushort* __restrict__ ub, float2* __restrict__ est){
    int bh = blockIdx.x, h = bh & (HH-1);
    int tid = threadIdx.x, wave = tid >> 6, lane = tid & 63;
    int m16 = lane & 15, kg = lane >> 4;
    const ushort* Vh = V2b + (size_t)h*8192;
    const ushort* ux = ub + (size_t)bh*LL;
    f32x4 acc[4] = {};
    #pragma unroll
    for (int k0 = 0; k0 < 128; k0 += 32){
        s16x8 fa = *(const s16x8*)&Vh[(wave*16 + m16)*128 + k0 + kg*8];
        #pragma unroll
        for (int nf = 0; nf < 4; ++nf){
            s16x8 fb = *(const s16x8*)&ux[(size_t)(nf*16 + m16)*128 + k0 + kg*8];
            acc[nf] = __builtin_amdgcn_mfma_f32_16x16x32_bf16(fa, fb, acc[nf], 0, 0, 0);
        }
    }
    #pragma unroll
    for (int nf = 0; nf < 4; ++nf){
        int c = nf*16 + m16;
        #pragma unroll
        for (int r = 0; r < 4; ++r){
            int srow = wave*16 + kg*4 + r;
            float* dst = (float*)&est[((size_t)bh*CH + c)*NN + (srow & 31)];
            dst[srow >> 5] = acc[nf][r];        // .x = re (rows 0..31), .y = im (rows 32..63)
        }
    }
}

// ---------------- scan pass B: prefix over chunks -> bf16 carry operands ----------------
__global__ void k_scan_B(const float4* __restrict__ par, const float2* __restrict__ est,
                         ushort* __restrict__ carr){
    int i = blockIdx.x * 256 + threadIdx.x;    // < B*H*N
    int n = i & 31, bh = i >> 5, h = bh & (HH-1);
    float4 p0 = par[h*NN + n];
    float wre = p0.z, wim = p0.w;              // w^T
    float cre = 0.f, cim = 0.f;
    const float2* e = est + (size_t)bh*CH*NN + n;
    ushort* cb = carr + (size_t)bh*CH*64;
    for (int c = 0; c < CH; ++c){
        cb[c*64 + n]      = f2bf(cre);
        cb[c*64 + 32 + n] = f2bf(cim);
        float2 v = e[(size_t)c*NN];
        float nre = fmaf(wre, cre, fmaf(-wim, cim, v.x));
        float nim = fmaf(wre, cim, fmaf(wim, cre, v.y));
        cre = nre; cim = nim;
    }
}

// ---------------- scan pass C (GEMM): Y = Tk@U + M2@C, fused GELU -> bf16 (B,H,L) ----------------
__global__ void __launch_bounds__(256) k_gemmC(const ushort* __restrict__ Tkb,
                        const ushort* __restrict__ M2b, const ushort* __restrict__ ub,
                        const ushort* __restrict__ carr, ushort* __restrict__ gy){
    int bh = blockIdx.x, h = bh & (HH-1);
    int tid = threadIdx.x, wave = tid >> 6, lane = tid & 63;
    int m16 = lane & 15, kg = lane >> 4;
    const ushort* Th = Tkb + (size_t)h*16384;
    const ushort* Mh = M2b + (size_t)h*8192;
    const ushort* ux = ub + (size_t)bh*LL;
    const ushort* cb = carr + (size_t)bh*CH*64;
    f32x4 acc[2][4] = {};
    #pragma unroll
    for (int k0 = 0; k0 < 128; k0 += 32){
        s16x8 fa0 = *(const s16x8*)&Th[(size_t)(wave*32 + m16)*128 + k0 + kg*8];
        s16x8 fa1 = *(const s16x8*)&Th[(size_t)(wave*32 + 16 + m16)*128 + k0 + kg*8];
        #pragma unroll
        for (int nf = 0; nf < 4; ++nf){
            s16x8 fb = *(const s16x8*)&ux[(size_t)(nf*16 + m16)*128 + k0 + kg*8];
            acc[0][nf] = __builtin_amdgcn_mfma_f32_16x16x32_bf16(fa0, fb, acc[0][nf], 0, 0, 0);
            acc[1][nf] = __builtin_amdgcn_mfma_f32_16x16x32_bf16(fa1, fb, acc[1][nf], 0, 0, 0);
        }
    }
    #pragma unroll
    for (int k0 = 0; k0 < 64; k0 += 32){
        s16x8 fa0 = *(const s16x8*)&Mh[(wave*32 + m16)*64 + k0 + kg*8];
        s16x8 fa1 = *(const s16x8*)&Mh[(wave*32 + 16 + m16)*64 + k0 + kg*8];
        #pragma unroll
        for (int nf = 0; nf < 4; ++nf){
            s16x8 fb = *(const s16x8*)&cb[(nf*16 + m16)*64 + k0 + kg*8];
            acc[0][nf] = __builtin_amdgcn_mfma_f32_16x16x32_bf16(fa0, fb, acc[0][nf], 0, 0, 0);
            acc[1][nf] = __builtin_amdgcn_mfma_f32_16x16x32_bf16(fa1, fb, acc[1][nf], 0, 0, 0);
        }
    }
    #pragma unroll
    for (int mf = 0; mf < 2; ++mf){
        #pragma unroll
        for (int nf = 0; nf < 4; ++nf){
            int c = nf*16 + m16;
            int t0 = wave*32 + mf*16 + kg*4;
            s16x4 pk;
            #pragma unroll
            for (int r = 0; r < 4; ++r){
                pk[r] = (short)f2bf(fast_gelu(acc[mf][nf][r]));
            }
            *(s16x4*)&gy[(size_t)bh*LL + c*TT + t0] = pk;
        }
    }
}

// ---------------- transpose (B,H,L) bf16 -> (B,L,H) bf16 ----------------
__global__ void k_transpose(const ushort* __restrict__ in, ushort* __restrict__ out){
    __shared__ ushort tile[64][66];
    int tid = threadIdx.x;
    int lt = blockIdx.x, ht = blockIdx.y, b = blockIdx.z;
    const ushort* ib = in + ((size_t)b*HH + ht*64)*LL + lt*64;
    #pragma unroll
    for (int k = 0; k < 16; ++k){
        int j = tid + k*256;
        tile[j >> 6][j & 63] = ib[(size_t)(j >> 6)*LL + (j & 63)];
    }
    __syncthreads();
    ushort* obp = out + ((size_t)b*LL + lt*64)*HH + ht*64;
    #pragma unroll
    for (int k = 0; k < 16; ++k){
        int j = tid + k*256;
        obp[(size_t)(j >> 6)*HH + (j & 63)] = tile[j & 63][j >> 6];
    }
}

// ---------------- GLU GEMM (LDS single-buffer + XOR swizzle): mid = x + a*sigmoid(g) ----------------
// Block: 64 a-channels + matching g-channels x 128 positions. A rows 0..63 = W a-rows,
// rows 64..127 = W g-rows. Swizzle: LDS(row,chunk) = Global(row, chunk ^ (row&7)) [rule #21].
__global__ void __launch_bounds__(256) k_glu(const ushort* __restrict__ Wg, const ushort* __restrict__ Xt,
                     const float* __restrict__ x, const float* __restrict__ gb,
                     float* __restrict__ mid){
    __shared__ __align__(16) ushort sh[16384];        // A[128][64]@0, B[128][64]@8192
    int tid = threadIdx.x;
    int w = tid >> 6, lane = tid & 63;
    int m16 = lane & 15, kg = lane >> 4;
    int wr = w >> 1, wc = w & 1;
    int p0  = blockIdx.x * 128;                       // global position tile (b*L+l)
    int oa0 = blockIdx.y * 64;                        // a-channel tile; g at +256
    const ushort* Brow = Xt + (size_t)p0*256;
    int srow = lane >> 3;
    int scol = ((lane & 7) ^ (srow & 7)) * 8;         // pre-swizzled global source
    f32x4 aa[2][4] = {}; f32x4 ag[2][4] = {};

    for (int kt = 0; kt < 4; ++kt){
        int k0s = kt*64;
        #pragma unroll
        for (int i = 0; i < 4; ++i){
            int rr = (w*4 + i)*8;
            int grow = (rr < 64) ? (oa0 + rr + srow) : (256 + oa0 + (rr - 64) + srow);
            __builtin_amdgcn_global_load_lds(
                (const __attribute__((address_space(1))) u32*)(Wg + (size_t)grow*256 + k0s + scol),
                (__attribute__((address_space(3))) u32*)&sh[rr*64], 16, 0, 0);
            __builtin_amdgcn_global_load_lds(
                (const __attribute__((address_space(1))) u32*)(Brow + (size_t)(rr + srow)*256 + k0s + scol),
                (__attribute__((address_space(3))) u32*)&sh[8192 + rr*64], 16, 0, 0);
        }
        __syncthreads();
        #pragma unroll
        for (int k032 = 0; k032 < 64; k032 += 32){
            int c = (k032 >> 3) + kg;                 // chunk 0..7
            s16x8 fa[2], fg[2], fb[4];
            #pragma unroll
            for (int i = 0; i < 2; ++i){
                int ra = wr*32 + i*16 + m16;
                int rg = 64 + wr*32 + i*16 + m16;
                fa[i] = *(const s16x8*)&sh[ra*64 + ((c ^ (ra & 7)) << 3)];
                fg[i] = *(const s16x8*)&sh[rg*64 + ((c ^ (rg & 7)) << 3)];
            }
            #pragma unroll
            for (int i = 0; i < 4; ++i){
                int rb = wc*64 + i*16 + m16;
                fb[i] = *(const s16x8*)&sh[8192 + rb*64 + ((c ^ (rb & 7)) << 3)];
            }
            #pragma unroll
            for (int mf = 0; mf < 2; ++mf){
                #pragma unroll
                for (int nf = 0; nf < 4; ++nf){
                    aa[mf][nf] = __builtin_amdgcn_mfma_f32_16x16x32_bf16(fa[mf], fb[nf], aa[mf][nf], 0, 0, 0);
                    ag[mf][nf] = __builtin_amdgcn_mfma_f32_16x16x32_bf16(fg[mf], fb[nf], ag[mf][nf], 0, 0, 0);
                }
            }
        }
        __syncthreads();
    }

    #pragma unroll
    for (int mf = 0; mf < 2; ++mf){
        #pragma unroll
        for (int nf = 0; nf < 4; ++nf){
            int pc = p0 + wc*64 + nf*16 + m16;
            int b = pc >> 13, l = pc & (LL-1);
            #pragma unroll
            for (int r = 0; r < 4; ++r){
                int o = oa0 + wr*32 + mf*16 + kg*4 + r;
                float va  = aa[mf][nf][r] + gb[o];
                float vg  = ag[mf][nf][r] + gb[o + 256];
                float sig = fast_sigmoid(vg);
                size_t idx = ((size_t)(b*HH + o) << 13) + l;
                mid[idx] = x[idx] + va*sig;
            }
        }
    }
}

// ---------------- unified m97-style GEMM: single-buffer LDS + XOR swizzle ----------------
// A = W [NCH x KDIM] row-major, B = acts [rows x KDIM] row-major (group-local rows).
// Block tile: 128 out-channels x 128 positions; wave tile 64x64; BK=64; 2-barrier loop.
// Swizzle: LDS(row,chunk) = Global(row, chunk ^ (row&7)) [rule #21].
// EPI 0: ffn1 (bias+gelu -> bf16 f1[pos][1024], LDS-staged full-line stores)
// EPI 1: ffn2 (mid + acc + bias -> fp32 out, (B,H,L))
template<int KDIM, int EPI>
__global__ void __launch_bounds__(256) k_gemm_lds(const ushort* __restrict__ A,
                      const ushort* __restrict__ Bm, const float* __restrict__ bias,
                      const float* __restrict__ mid, void* __restrict__ Cout, int pbase){
    __shared__ __align__(16) ushort sh[17408];        // A[128][64]@0, B[128][64]@8192; epi lt[128][136]
    int tid = threadIdx.x;
    int w = tid >> 6, lane = tid & 63;
    int m16 = lane & 15, kg = lane >> 4;
    int wr = w >> 1, wc = w & 1;
    int q0  = blockIdx.x * 128;                       // group-local position tile
    int oc0 = blockIdx.y * 128;                       // output-channel tile
    const ushort* Arow = A  + (size_t)oc0*KDIM;
    const ushort* Brow = Bm + (size_t)q0*KDIM;
    int srow = lane >> 3;
    int scol = ((lane & 7) ^ (srow & 7)) * 8;         // pre-swizzled global source
    f32x4 acc[4][4] = {};
    const int nK = KDIM/64;

    for (int kt = 0; kt < nK; ++kt){
        int k0s = kt*64;
        #pragma unroll
        for (int i = 0; i < 4; ++i){
            int rr = (w*4 + i)*8;
            __builtin_amdgcn_global_load_lds(
                (const __attribute__((address_space(1))) u32*)(Arow + (size_t)(rr + srow)*KDIM + k0s + scol),
                (__attribute__((address_space(3))) u32*)&sh[rr*64], 16, 0, 0);
            __builtin_amdgcn_global_load_lds(
                (const __attribute__((address_space(1))) u32*)(Brow + (size_t)(rr + srow)*KDIM + k0s + scol),
                (__attribute__((address_space(3))) u32*)&sh[8192 + rr*64], 16, 0, 0);
        }
        __syncthreads();
        #pragma unroll
        for (int k032 = 0; k032 < 64; k032 += 32){
            int c = (k032 >> 3) + kg;                 // chunk 0..7
            s16x8 af[4], bf[4];
            #pragma unroll
            for (int i = 0; i < 4; ++i){
                int ra = wr*64 + i*16 + m16;
                int rb = wc*64 + i*16 + m16;
                af[i] = *(const s16x8*)&sh[ra*64 + ((c ^ (ra & 7)) << 3)];
                bf[i] = *(const s16x8*)&sh[8192 + rb*64 + ((c ^ (rb & 7)) << 3)];
            }
            #pragma unroll
            for (int mf = 0; mf < 4; ++mf){
                #pragma unroll
                for (int nf = 0; nf < 4; ++nf)
                    acc[mf][nf] = __builtin_amdgcn_mfma_f32_16x16x32_bf16(af[mf], bf[nf], acc[mf][nf], 0, 0, 0);
            }
        }
        __syncthreads();
    }

    if (EPI == 0){
        // bias+gelu -> bf16, staged through LDS for full-line stores (136: rows 16B-aligned)
        ushort (*lt)[136] = (ushort(*)[136])sh;
        #pragma unroll
        for (int mf = 0; mf < 4; ++mf){
            #pragma unroll
            for (int nf = 0; nf < 4; ++nf){
                int lr = wc*64 + nf*16 + m16;
                int lc = wr*64 + mf*16 + kg*4;
                s16x4 pk;
                #pragma unroll
                for (int r = 0; r < 4; ++r){
                    float v = acc[mf][nf][r] + bias[oc0 + lc + r];
                    pk[r] = (short)f2bf(fast_gelu(v));
                }
                *(s16x4*)&lt[lr][lc] = pk;
            }
        }
        __syncthreads();
        ushort* f1 = (ushort*)Cout;
        #pragma unroll
        for (int i = 0; i < 8; ++i){
            int chunk = i*256 + tid;
            int row = chunk >> 4, c16 = chunk & 15;
            s16x8 v = *(const s16x8*)&lt[row][c16*8];
            *(s16x8*)&f1[((size_t)(q0 + row) << 10) + oc0 + c16*8] = v;
        }
    } else {
        float* out = (float*)Cout;
        #pragma unroll
        for (int mf = 0; mf < 4; ++mf){
            #pragma unroll
            for (int nf = 0; nf < 4; ++nf){
                int pc = pbase + q0 + wc*64 + nf*16 + m16;
                int b = pc >> 13, l = pc & (LL-1);
                #pragma unroll
                for (int r = 0; r < 4; ++r){
                    int oc = oc0 + wr*64 + mf*16 + kg*4 + r;
                    size_t idx = ((size_t)(b*HH + oc) << 13) + l;
                    out[idx] = mid[idx] + acc[mf][nf][r] + bias[oc];
                }
            }
        }
    }
}

extern "C" void kernel_launch(void* const* d_in, const int* in_sizes, int n_in,
                              void* d_out, int out_size, void* d_ws, size_t ws_size,
                              hipStream_t stream) {
    const float* x          = (const float*)d_in[0];
    const float* ln1_g      = (const float*)d_in[1];
    const float* ln1_b      = (const float*)d_in[2];
    const float* ln2_g      = (const float*)d_in[3];
    const float* ln2_b      = (const float*)d_in[4];
    const float* log_dt     = (const float*)d_in[5];
    const float* log_A_real = (const float*)d_in[6];
    const float* A_imag     = (const float*)d_in[7];
    const float* C_re       = (const float*)d_in[8];
    const float* C_im       = (const float*)d_in[9];
    const float* Dv         = (const float*)d_in[10];
    const float* glu_w      = (const float*)d_in[11];
    const float* glu_b      = (const float*)d_in[12];
    const float* ffn_in_w   = (const float*)d_in[13];
    const float* ffn_in_b   = (const float*)d_in[14];
    const float* ffn_out_w  = (const float*)d_in[15];
    const float* ffn_out_b  = (const float*)d_in[16];
    float* out = (float*)d_out;

    char* ws = (char*)d_ws;
    const size_t MB = 1u << 20;
    // lifetime-aliased layout (high-water 52 + 16*G MB):
    float4* par  = (float4*)(ws);                 // 128 KB
    ushort* wglu = (ushort*)(ws + 256*1024);      // 256 KB
    ushort* wfi  = (ushort*)(ws + 512*1024);      // 512 KB
    ushort* wfo  = (ushort*)(ws + 1024*1024);     // 512 KB
    ushort* Tkb  = (ushort*)(ws + 2*MB);          // 8 MB  [2,10)   dead after gemmC
    ushort* M2b  = (ushort*)(ws + 10*MB);         // 4 MB  [10,14)  dead after gemmC
    ushort* V2b  = (ushort*)(ws + 14*MB);         // 4 MB  [14,18)  dead after gemmA
    ushort* ub   = (ushort*)(ws + 18*MB);         // 16 MB [18,34)  dead after gemmC
    float2* est  = (float2*)(ws + 34*MB);         // 16 MB [34,50)  dead after scan_B
    ushort* carr = (ushort*)(ws + 50*MB);         // 8 MB  [50,58)  dead after gemmC
    ushort* gy   = (ushort*)(ws + 34*MB);         // 16 MB reuse est; dead after transpose
    ushort* gyt  = (ushort*)(ws + 50*MB);         // 16 MB [50,66) reuse carr; dead after glu
    float*  mid  = (float*)(ws + 2*MB);           // 34 MB [2,36) reuse Tkb..ub (+2MB of dead gy)
    ushort* x2t  = (ushort*)(ws + 36*MB);         // 16 MB [36,52) reuse gy tail (dead) and gyt head (dead after glu)
    ushort* f1   = (ushort*)(ws + 52*MB);         // 16*G MB [52,52+16G)

    int G = (ws_size >= 117*MB) ? 4 : ((ws_size >= 85*MB) ? 2 : 1);

    k_prep_weights<<<1024, 256, 0, stream>>>(glu_w, ffn_in_w, ffn_out_w, wglu, wfi, wfo);
    k_scan_params<<<32, 256, 0, stream>>>(log_dt, log_A_real, A_imag, par);
    k_build<<<HH, 256, 0, stream>>>(log_dt, log_A_real, A_imag, C_re, C_im, Dv, Tkb, M2b, V2b);
    k_ln<2><<<BB*LL/64, 256, 0, stream>>>(x, ub, ln1_g, ln1_b);
    k_gemmA<<<BB*HH, 256, 0, stream>>>(V2b, ub, est);
    k_scan_B<<<BB*HH*NN/256, 256, 0, stream>>>(par, est, carr);
    k_gemmC<<<BB*HH, 256, 0, stream>>>(Tkb, M2b, ub, carr, gy);
    k_transpose<<<dim3(LL/64, HH/64, BB), 256, 0, stream>>>(gy, gyt);
    k_glu<<<dim3(BB*LL/128, 4), 256, 0, stream>>>(wglu, gyt, x, glu_b, mid);
    k_ln<1><<<BB*LL/64, 256, 0, stream>>>(mid, x2t, ln2_g, ln2_b);
    for (int b0 = 0; b0 < BB; b0 += G){
        int pbase = b0 * LL;
        k_gemm_lds<256,0><<<dim3(G*LL/128, 8), 256, 0, stream>>>(
            wfi, x2t + (size_t)pbase*256, ffn_in_b, nullptr, f1, 0);
        k_gemm_lds<1024,1><<<dim3(G*LL/128, 2), 256, 0, stream>>>(
            wfo, f1, ffn_out_b, mid, out, pbase);
    }
    (void)in_sizes; (void)n_in; (void)out_size; (void)ws_size;
}

// Round 11
// 304.607 us; speedup vs baseline: 1.0614x; 1.0614x over previous
//
#include <hip/hip_runtime.h>
#include <hip/hip_bf16.h>

#define BB 4
#define HH 256
#define LL 8192
#define NN 32
#define CH 64      // chunks per (b,h)
#define TT 128     // chunk length; CH*TT == LL

typedef __attribute__((ext_vector_type(4))) float f32x4;
typedef __attribute__((ext_vector_type(8))) short s16x8;
typedef __attribute__((ext_vector_type(4))) short s16x4;
typedef unsigned int u32;

static __device__ __forceinline__ ushort f2bf(float f){
    union { float f; unsigned int i; } v; v.f = f;
    unsigned int x = v.i;
    return (ushort)((x + 0x7fffu + ((x >> 16) & 1u)) >> 16);   // RNE
}

// branch-free GELU (tanh form, native exp2/rcp). |err| <~1e-3 abs, << bf16 path noise.
static __device__ __forceinline__ float fast_gelu(float x){
    float x3 = x*x*x;
    float z  = fmaf(0.03567740814f, x3, 0.7978845608f*x);
    float e  = __builtin_amdgcn_exp2f(z * 2.885390082f);       // exp(2z)
    float t  = 1.f - 2.f*__builtin_amdgcn_rcpf(e + 1.f);       // tanh(z)
    return 0.5f*x*(1.f + t);
}
static __device__ __forceinline__ float fast_sigmoid(float x){
    float e = __builtin_amdgcn_exp2f(-x * 1.442695041f);       // exp(-x)
    return __builtin_amdgcn_rcpf(1.f + e);
}

// ---------------- weight conversion fp32 -> bf16 ----------------
__global__ void k_prep_weights(const float* __restrict__ gw, const float* __restrict__ fiw,
                               const float* __restrict__ fow,
                               ushort* __restrict__ dglu, ushort* __restrict__ dfi,
                               ushort* __restrict__ dfo){
    int i = blockIdx.x * 256 + threadIdx.x;           // grid covers 262144
    if (i < 512*256)  dglu[i] = f2bf(gw[i]);
    if (i < 1024*256) dfi[i]  = f2bf(fiw[i]);
    if (i < 1024*256) dfo[i]  = f2bf(fow[i]);
}

// ---------------- scan parameters: w, w^T per (h,n) ----------------
__global__ void k_scan_params(const float* __restrict__ log_dt, const float* __restrict__ log_A_real,
                              const float* __restrict__ A_imag, float4* __restrict__ out){
    int i = blockIdx.x * 256 + threadIdx.x;           // < H*N = 8192
    int h = i >> 5;
    float dt  = expf(log_dt[h]);
    float Are = -expf(log_A_real[i]);
    float Aim = A_imag[i];
    float xr = Are * dt, xi = Aim * dt;               // dtA
    float er = expf(xr), sn, cs;
    sincosf(xi, &sn, &cs);
    float erT = expf(xr * (float)TT), snT, csT;
    sincosf(xi * (float)TT, &snT, &csT);
    out[i] = make_float4(er*cs, er*sn, erT*csT, erT*snT);   // w, w^T
}

// ---------------- build per-h GEMM operands: Toeplitz Tk, carry M2, end-state V2 ----------------
__global__ void __launch_bounds__(256) k_build(const float* __restrict__ log_dt,
      const float* __restrict__ log_A_real, const float* __restrict__ A_imag,
      const float* __restrict__ C_re, const float* __restrict__ C_im, const float* __restrict__ Dp,
      ushort* __restrict__ Tkb, ushort* __restrict__ M2b, ushort* __restrict__ V2b){
    int h = blockIdx.x, tid = threadIdx.x;
    __shared__ float prm[4][32];            // xr, xi, ccre, ccim
    __shared__ float2 pw[129][32];          // w^d
    __shared__ float kk[129];               // real kernel k[d]
    if (tid < 32){
        int n = tid, i = h*NN + n;
        float dt  = expf(log_dt[h]);
        float Are = -expf(log_A_real[i]);
        float Aim = A_imag[i];
        float xr = Are*dt, xi = Aim*dt;
        float er = expf(xr), sn, cs; sincosf(xi, &sn, &cs);
        float wre = er*cs, wim = er*sn;
        float nre = wre - 1.f, nim = wim;
        float inv = 1.f / (Are*Are + Aim*Aim);
        float qre = (nre*Are + nim*Aim) * inv;
        float qim = (nim*Are - nre*Aim) * inv;
        float cre = C_re[i], cim = C_im[i];
        prm[0][n] = xr; prm[1][n] = xi;
        prm[2][n] = 2.f*(cre*qre - cim*qim);      // ccre (2*Cc)
        prm[3][n] = 2.f*(cre*qim + cim*qre);      // ccim
    }
    __syncthreads();
    if (tid < 129){
        float d = (float)tid, acc = 0.f;
        for (int n = 0; n < 32; ++n){
            float er = expf(prm[0][n]*d), sn, cs; sincosf(prm[1][n]*d, &sn, &cs);
            float pre = er*cs, pim = er*sn;
            pw[tid][n] = make_float2(pre, pim);
            acc += prm[2][n]*pre - prm[3][n]*pim;
        }
        kk[tid] = acc;
    }
    __syncthreads();
    float k0d = kk[0] + Dp[h];
    for (int idx = tid; idx < 128*128; idx += 256){       // Tk[t][tau]
        int t = idx >> 7, ta = idx & 127, d = t - ta;
        float v = (d < 0) ? 0.f : ((d == 0) ? k0d : kk[d]);
        Tkb[(size_t)h*16384 + idx] = f2bf(v);
    }
    for (int idx = tid; idx < 128*64; idx += 256){        // M2[t][0:32]=Re(cc w^{t+1}); [32:64]=-Im
        int t = idx >> 6, j = idx & 63, n = j & 31;
        float2 p = pw[t+1][n];
        float v = (j < 32) ?  (prm[2][n]*p.x - prm[3][n]*p.y)
                           : -(prm[2][n]*p.y + prm[3][n]*p.x);
        M2b[(size_t)h*8192 + idx] = f2bf(v);
    }
    for (int idx = tid; idx < 64*128; idx += 256){        // V2[row][tau] = re/im of w^{127-tau}
        int row = idx >> 7, ta = idx & 127, n = row & 31;
        float2 p = pw[127 - ta][n];
        V2b[(size_t)h*8192 + idx] = f2bf(row < 32 ? p.x : p.y);
    }
}

// ---------------- channel LayerNorm (over H at each (b,l)) ----------------
// MODE 1: bf16 out, transposed (B,L,H). MODE 2: bf16 out, (B,H,L).
template<int MODE>
__global__ void __launch_bounds__(256) k_ln(const float* __restrict__ in, void* __restrict__ outp,
                     const float* __restrict__ gamma, const float* __restrict__ beta){
    int p = threadIdx.x & 63, cg = threadIdx.x >> 6;
    int b  = blockIdx.x / (LL/64);
    int l  = (blockIdx.x % (LL/64)) * 64 + p;
    const float* base = in + (size_t)b*HH*LL + l;
    int c0 = cg * 64;
    float s = 0.f, s2 = 0.f;
    #pragma unroll 8
    for (int j = 0; j < 64; ++j){
        float v = base[(size_t)(c0+j)*LL];
        s += v; s2 += v*v;
    }
    __shared__ float red[2][4][64];
    red[0][cg][p] = s; red[1][cg][p] = s2;
    __syncthreads();
    float ts = red[0][0][p]+red[0][1][p]+red[0][2][p]+red[0][3][p];
    float tq = red[1][0][p]+red[1][1][p]+red[1][2][p]+red[1][3][p];
    float mu   = ts * (1.f/HH);
    float var  = tq * (1.f/HH) - mu*mu;
    float rstd = rsqrtf(var + 1e-5f);
    if (MODE == 1){
        ushort* ob = (ushort*)outp + ((size_t)(b*LL + l))*HH + c0;
        #pragma unroll
        for (int j8 = 0; j8 < 8; ++j8){
            s16x8 v;
            #pragma unroll
            for (int e = 0; e < 8; ++e){
                int c = c0 + j8*8 + e;
                v[e] = (short)f2bf((base[(size_t)c*LL] - mu)*rstd*gamma[c] + beta[c]);
            }
            *(s16x8*)(ob + j8*8) = v;
        }
    } else {
        ushort* ob = (ushort*)outp + (size_t)b*HH*LL + l;
        #pragma unroll 8
        for (int j = 0; j < 64; ++j){
            int c = c0 + j;
            ob[(size_t)c*LL] = f2bf((base[(size_t)c*LL] - mu)*rstd*gamma[c] + beta[c]);
        }
    }
}

// ---------------- scan pass A (GEMM): E[64 x CH] = V2_h @ U ----------------
__global__ void __launch_bounds__(256) k_gemmA(const ushort* __restrict__ V2b,
                        const ushort* __restrict__ ub, float2* __restrict__ est){
    int bh = blockIdx.x, h = bh & (HH-1);
    int tid = threadIdx.x, wave = tid >> 6, lane = tid & 63;
    int m16 = lane & 15, kg = lane >> 4;
    const ushort* Vh = V2b + (size_t)h*8192;
    const ushort* ux = ub + (size_t)bh*LL;
    f32x4 acc[4] = {};
    #pragma unroll
    for (int k0 = 0; k0 < 128; k0 += 32){
        s16x8 fa = *(const s16x8*)&Vh[(wave*16 + m16)*128 + k0 + kg*8];
        #pragma unroll
        for (int nf = 0; nf < 4; ++nf){
            s16x8 fb = *(const s16x8*)&ux[(size_t)(nf*16 + m16)*128 + k0 + kg*8];
            acc[nf] = __builtin_amdgcn_mfma_f32_16x16x32_bf16(fa, fb, acc[nf], 0, 0, 0);
        }
    }
    #pragma unroll
    for (int nf = 0; nf < 4; ++nf){
        int c = nf*16 + m16;
        #pragma unroll
        for (int r = 0; r < 4; ++r){
            int srow = wave*16 + kg*4 + r;
            float* dst = (float*)&est[((size_t)bh*CH + c)*NN + (srow & 31)];
            dst[srow >> 5] = acc[nf][r];        // .x = re (rows 0..31), .y = im (rows 32..63)
        }
    }
}

// ---------------- scan pass B: prefix over chunks -> bf16 carry operands ----------------
__global__ void k_scan_B(const float4* __restrict__ par, const float2* __restrict__ est,
                         ushort* __restrict__ carr){
    int i = blockIdx.x * 256 + threadIdx.x;    // < B*H*N
    int n = i & 31, bh = i >> 5, h = bh & (HH-1);
    float4 p0 = par[h*NN + n];
    float wre = p0.z, wim = p0.w;              // w^T
    float cre = 0.f, cim = 0.f;
    const float2* e = est + (size_t)bh*CH*NN + n;
    ushort* cb = carr + (size_t)bh*CH*64;
    for (int c = 0; c < CH; ++c){
        cb[c*64 + n]      = f2bf(cre);
        cb[c*64 + 32 + n] = f2bf(cim);
        float2 v = e[(size_t)c*NN];
        float nre = fmaf(wre, cre, fmaf(-wim, cim, v.x));
        float nim = fmaf(wre, cim, fmaf(wim, cre, v.y));
        cre = nre; cim = nim;
    }
}

// ---------------- scan pass C (GEMM): Y = Tk@U + M2@C, fused GELU -> bf16 (B,H,L) ----------------
__global__ void __launch_bounds__(256) k_gemmC(const ushort* __restrict__ Tkb,
                        const ushort* __restrict__ M2b, const ushort* __restrict__ ub,
                        const ushort* __restrict__ carr, ushort* __restrict__ gy){
    int bh = blockIdx.x, h = bh & (HH-1);
    int tid = threadIdx.x, wave = tid >> 6, lane = tid & 63;
    int m16 = lane & 15, kg = lane >> 4;
    const ushort* Th = Tkb + (size_t)h*16384;
    const ushort* Mh = M2b + (size_t)h*8192;
    const ushort* ux = ub + (size_t)bh*LL;
    const ushort* cb = carr + (size_t)bh*CH*64;
    f32x4 acc[2][4] = {};
    #pragma unroll
    for (int k0 = 0; k0 < 128; k0 += 32){
        s16x8 fa0 = *(const s16x8*)&Th[(size_t)(wave*32 + m16)*128 + k0 + kg*8];
        s16x8 fa1 = *(const s16x8*)&Th[(size_t)(wave*32 + 16 + m16)*128 + k0 + kg*8];
        #pragma unroll
        for (int nf = 0; nf < 4; ++nf){
            s16x8 fb = *(const s16x8*)&ux[(size_t)(nf*16 + m16)*128 + k0 + kg*8];
            acc[0][nf] = __builtin_amdgcn_mfma_f32_16x16x32_bf16(fa0, fb, acc[0][nf], 0, 0, 0);
            acc[1][nf] = __builtin_amdgcn_mfma_f32_16x16x32_bf16(fa1, fb, acc[1][nf], 0, 0, 0);
        }
    }
    #pragma unroll
    for (int k0 = 0; k0 < 64; k0 += 32){
        s16x8 fa0 = *(const s16x8*)&Mh[(wave*32 + m16)*64 + k0 + kg*8];
        s16x8 fa1 = *(const s16x8*)&Mh[(wave*32 + 16 + m16)*64 + k0 + kg*8];
        #pragma unroll
        for (int nf = 0; nf < 4; ++nf){
            s16x8 fb = *(const s16x8*)&cb[(nf*16 + m16)*64 + k0 + kg*8];
            acc[0][nf] = __builtin_amdgcn_mfma_f32_16x16x32_bf16(fa0, fb, acc[0][nf], 0, 0, 0);
            acc[1][nf] = __builtin_amdgcn_mfma_f32_16x16x32_bf16(fa1, fb, acc[1][nf], 0, 0, 0);
        }
    }
    #pragma unroll
    for (int mf = 0; mf < 2; ++mf){
        #pragma unroll
        for (int nf = 0; nf < 4; ++nf){
            int c = nf*16 + m16;
            int t0 = wave*32 + mf*16 + kg*4;
            s16x4 pk;
            #pragma unroll
            for (int r = 0; r < 4; ++r){
                pk[r] = (short)f2bf(fast_gelu(acc[mf][nf][r]));
            }
            *(s16x4*)&gy[(size_t)bh*LL + c*TT + t0] = pk;
        }
    }
}

// ---------------- transpose (B,H,L) bf16 -> (B,L,H) bf16 ----------------
__global__ void k_transpose(const ushort* __restrict__ in, ushort* __restrict__ out){
    __shared__ ushort tile[64][66];
    int tid = threadIdx.x;
    int lt = blockIdx.x, ht = blockIdx.y, b = blockIdx.z;
    const ushort* ib = in + ((size_t)b*HH + ht*64)*LL + lt*64;
    #pragma unroll
    for (int k = 0; k < 16; ++k){
        int j = tid + k*256;
        tile[j >> 6][j & 63] = ib[(size_t)(j >> 6)*LL + (j & 63)];
    }
    __syncthreads();
    ushort* obp = out + ((size_t)b*LL + lt*64)*HH + ht*64;
    #pragma unroll
    for (int k = 0; k < 16; ++k){
        int j = tid + k*256;
        obp[(size_t)(j >> 6)*HH + (j & 63)] = tile[j & 63][j >> 6];
    }
}

// ---------------- GLU GEMM (dbuf LDS + XOR swizzle): mid = x + a*sigmoid(g) ----------------
// Block: 64 a-channels + matching g-channels x 128 positions. A rows 0..63 = W a-rows,
// rows 64..127 = W g-rows. Swizzle: LDS(row,chunk) = Global(row, chunk ^ (row&7)) [rule #21].
__global__ void __launch_bounds__(256) k_glu(const ushort* __restrict__ Wg, const ushort* __restrict__ Xt,
                     const float* __restrict__ x, const float* __restrict__ gb,
                     float* __restrict__ mid){
    __shared__ __align__(16) ushort sh[32768];        // A[2][128][64]@0, B[2][128][64]@16384
    int tid = threadIdx.x;
    int w = tid >> 6, lane = tid & 63;
    int m16 = lane & 15, kg = lane >> 4;
    int wr = w >> 1, wc = w & 1;
    int p0  = blockIdx.x * 128;                       // global position tile (b*L+l)
    int oa0 = blockIdx.y * 64;                        // a-channel tile; g at +256
    const ushort* Brow = Xt + (size_t)p0*256;
    int srow = lane >> 3;
    int scol = ((lane & 7) ^ (srow & 7)) * 8;         // pre-swizzled global source
    f32x4 aa[2][4] = {}; f32x4 ag[2][4] = {};

    #define GSTAGE(buf, kt) { \
        int k0s = (kt)*64; \
        _Pragma("unroll") \
        for (int i = 0; i < 4; ++i){ \
            int rr = (w*4 + i)*8; \
            int grow = (rr < 64) ? (oa0 + rr + srow) : (256 + oa0 + (rr - 64) + srow); \
            __builtin_amdgcn_global_load_lds( \
                (const __attribute__((address_space(1))) u32*)(Wg + (size_t)grow*256 + k0s + scol), \
                (__attribute__((address_space(3))) u32*)&sh[(buf)*8192 + rr*64], 16, 0, 0); \
            __builtin_amdgcn_global_load_lds( \
                (const __attribute__((address_space(1))) u32*)(Brow + (size_t)(rr + srow)*256 + k0s + scol), \
                (__attribute__((address_space(3))) u32*)&sh[16384 + (buf)*8192 + rr*64], 16, 0, 0); \
        } }

    int buf = 0;
    GSTAGE(0, 0);
    __syncthreads();
    for (int kt = 0; kt < 4; ++kt){
        if (kt + 1 < 4) GSTAGE(buf^1, kt+1);
        #pragma unroll
        for (int k032 = 0; k032 < 64; k032 += 32){
            int c = (k032 >> 3) + kg;                 // chunk 0..7
            s16x8 fa[2], fg[2], fb[4];
            #pragma unroll
            for (int i = 0; i < 2; ++i){
                int ra = wr*32 + i*16 + m16;
                int rg = 64 + wr*32 + i*16 + m16;
                fa[i] = *(const s16x8*)&sh[buf*8192 + ra*64 + ((c ^ (ra & 7)) << 3)];
                fg[i] = *(const s16x8*)&sh[buf*8192 + rg*64 + ((c ^ (rg & 7)) << 3)];
            }
            #pragma unroll
            for (int i = 0; i < 4; ++i){
                int rb = wc*64 + i*16 + m16;
                fb[i] = *(const s16x8*)&sh[16384 + buf*8192 + rb*64 + ((c ^ (rb & 7)) << 3)];
            }
            #pragma unroll
            for (int mf = 0; mf < 2; ++mf){
                #pragma unroll
                for (int nf = 0; nf < 4; ++nf){
                    aa[mf][nf] = __builtin_amdgcn_mfma_f32_16x16x32_bf16(fa[mf], fb[nf], aa[mf][nf], 0, 0, 0);
                    ag[mf][nf] = __builtin_amdgcn_mfma_f32_16x16x32_bf16(fg[mf], fb[nf], ag[mf][nf], 0, 0, 0);
                }
            }
        }
        __syncthreads();
        buf ^= 1;
    }
    #undef GSTAGE

    #pragma unroll
    for (int mf = 0; mf < 2; ++mf){
        #pragma unroll
        for (int nf = 0; nf < 4; ++nf){
            int pc = p0 + wc*64 + nf*16 + m16;
            int b = pc >> 13, l = pc & (LL-1);
            #pragma unroll
            for (int r = 0; r < 4; ++r){
                int o = oa0 + wr*32 + mf*16 + kg*4 + r;
                float va  = aa[mf][nf][r] + gb[o];
                float vg  = ag[mf][nf][r] + gb[o + 256];
                float sig = fast_sigmoid(vg);
                size_t idx = ((size_t)(b*HH + o) << 13) + l;
                mid[idx] = x[idx] + va*sig;
            }
        }
    }
}

// ---------------- unified m97-style GEMM: dbuf LDS + XOR swizzle ----------------
// A = W [NCH x KDIM] row-major, B = acts [rows x KDIM] row-major (group-local rows).
// Block tile: 128 out-channels x 128 positions; wave tile 64x64; BK=64; prefetch dbuf.
// Swizzle: LDS(row,chunk) = Global(row, chunk ^ (row&7)) [rule #21].
// EPI 0: ffn1 (bias+gelu -> bf16 f1[pos][1024], LDS-staged full-line stores)
// EPI 1: ffn2 (mid + acc + bias -> fp32 out, (B,H,L))
template<int KDIM, int EPI>
__global__ void __launch_bounds__(256) k_gemm_lds(const ushort* __restrict__ A,
                      const ushort* __restrict__ Bm, const float* __restrict__ bias,
                      const float* __restrict__ mid, void* __restrict__ Cout, int pbase){
    __shared__ __align__(16) ushort sh[32768];        // A[2][128][64]@0, B[2][128][64]@16384; epi lt[128][136]
    int tid = threadIdx.x;
    int w = tid >> 6, lane = tid & 63;
    int m16 = lane & 15, kg = lane >> 4;
    int wr = w >> 1, wc = w & 1;
    int q0  = blockIdx.x * 128;                       // group-local position tile
    int oc0 = blockIdx.y * 128;                       // output-channel tile
    const ushort* Arow = A  + (size_t)oc0*KDIM;
    const ushort* Brow = Bm + (size_t)q0*KDIM;
    int srow = lane >> 3;
    int scol = ((lane & 7) ^ (srow & 7)) * 8;         // pre-swizzled global source
    f32x4 acc[4][4] = {};
    const int nK = KDIM/64;

    #define STAGE(buf, kt) { \
        int k0s = (kt)*64; \
        _Pragma("unroll") \
        for (int i = 0; i < 4; ++i){ \
            int rr = (w*4 + i)*8; \
            __builtin_amdgcn_global_load_lds( \
                (const __attribute__((address_space(1))) u32*)(Arow + (size_t)(rr + srow)*KDIM + k0s + scol), \
                (__attribute__((address_space(3))) u32*)&sh[(buf)*8192 + rr*64], 16, 0, 0); \
            __builtin_amdgcn_global_load_lds( \
                (const __attribute__((address_space(1))) u32*)(Brow + (size_t)(rr + srow)*KDIM + k0s + scol), \
                (__attribute__((address_space(3))) u32*)&sh[16384 + (buf)*8192 + rr*64], 16, 0, 0); \
        } }

    int buf = 0;
    STAGE(0, 0);
    __syncthreads();
    for (int kt = 0; kt < nK; ++kt){
        if (kt + 1 < nK) STAGE(buf^1, kt+1);
        #pragma unroll
        for (int k032 = 0; k032 < 64; k032 += 32){
            int c = (k032 >> 3) + kg;                 // chunk 0..7
            s16x8 af[4], bf[4];
            #pragma unroll
            for (int i = 0; i < 4; ++i){
                int ra = wr*64 + i*16 + m16;
                int rb = wc*64 + i*16 + m16;
                af[i] = *(const s16x8*)&sh[buf*8192 + ra*64 + ((c ^ (ra & 7)) << 3)];
                bf[i] = *(const s16x8*)&sh[16384 + buf*8192 + rb*64 + ((c ^ (rb & 7)) << 3)];
            }
            #pragma unroll
            for (int mf = 0; mf < 4; ++mf){
                #pragma unroll
                for (int nf = 0; nf < 4; ++nf)
                    acc[mf][nf] = __builtin_amdgcn_mfma_f32_16x16x32_bf16(af[mf], bf[nf], acc[mf][nf], 0, 0, 0);
            }
        }
        __syncthreads();
        buf ^= 1;
    }
    #undef STAGE

    if (EPI == 0){
        // bias+gelu -> bf16, staged through LDS for full-line stores (136: rows 16B-aligned)
        ushort (*lt)[136] = (ushort(*)[136])sh;
        #pragma unroll
        for (int mf = 0; mf < 4; ++mf){
            #pragma unroll
            for (int nf = 0; nf < 4; ++nf){
                int lr = wc*64 + nf*16 + m16;
                int lc = wr*64 + mf*16 + kg*4;
                s16x4 pk;
                #pragma unroll
                for (int r = 0; r < 4; ++r){
                    float v = acc[mf][nf][r] + bias[oc0 + lc + r];
                    pk[r] = (short)f2bf(fast_gelu(v));
                }
                *(s16x4*)&lt[lr][lc] = pk;
            }
        }
        __syncthreads();
        ushort* f1 = (ushort*)Cout;
        #pragma unroll
        for (int i = 0; i < 8; ++i){
            int chunk = i*256 + tid;
            int row = chunk >> 4, c16 = chunk & 15;
            s16x8 v = *(const s16x8*)&lt[row][c16*8];
            *(s16x8*)&f1[((size_t)(q0 + row) << 10) + oc0 + c16*8] = v;
        }
    } else {
        float* out = (float*)Cout;
        #pragma unroll
        for (int mf = 0; mf < 4; ++mf){
            #pragma unroll
            for (int nf = 0; nf < 4; ++nf){
                int pc = pbase + q0 + wc*64 + nf*16 + m16;
                int b = pc >> 13, l = pc & (LL-1);
                #pragma unroll
                for (int r = 0; r < 4; ++r){
                    int oc = oc0 + wr*64 + mf*16 + kg*4 + r;
                    size_t idx = ((size_t)(b*HH + oc) << 13) + l;
                    out[idx] = mid[idx] + acc[mf][nf][r] + bias[oc];
                }
            }
        }
    }
}

extern "C" void kernel_launch(void* const* d_in, const int* in_sizes, int n_in,
                              void* d_out, int out_size, void* d_ws, size_t ws_size,
                              hipStream_t stream) {
    const float* x          = (const float*)d_in[0];
    const float* ln1_g      = (const float*)d_in[1];
    const float* ln1_b      = (const float*)d_in[2];
    const float* ln2_g      = (const float*)d_in[3];
    const float* ln2_b      = (const float*)d_in[4];
    const float* log_dt     = (const float*)d_in[5];
    const float* log_A_real = (const float*)d_in[6];
    const float* A_imag     = (const float*)d_in[7];
    const float* C_re       = (const float*)d_in[8];
    const float* C_im       = (const float*)d_in[9];
    const float* Dv         = (const float*)d_in[10];
    const float* glu_w      = (const float*)d_in[11];
    const float* glu_b      = (const float*)d_in[12];
    const float* ffn_in_w   = (const float*)d_in[13];
    const float* ffn_in_b   = (const float*)d_in[14];
    const float* ffn_out_w  = (const float*)d_in[15];
    const float* ffn_out_b  = (const float*)d_in[16];
    float* out = (float*)d_out;

    char* ws = (char*)d_ws;
    const size_t MB = 1u << 20;
    // lifetime-aliased layout (high-water 52 + 16*G MB):
    float4* par  = (float4*)(ws);                 // 128 KB
    ushort* wglu = (ushort*)(ws + 256*1024);      // 256 KB
    ushort* wfi  = (ushort*)(ws + 512*1024);      // 512 KB
    ushort* wfo  = (ushort*)(ws + 1024*1024);     // 512 KB
    ushort* Tkb  = (ushort*)(ws + 2*MB);          // 8 MB  [2,10)   dead after gemmC
    ushort* M2b  = (ushort*)(ws + 10*MB);         // 4 MB  [10,14)  dead after gemmC
    ushort* V2b  = (ushort*)(ws + 14*MB);         // 4 MB  [14,18)  dead after gemmA
    ushort* ub   = (ushort*)(ws + 18*MB);         // 16 MB [18,34)  dead after gemmC
    float2* est  = (float2*)(ws + 34*MB);         // 16 MB [34,50)  dead after scan_B
    ushort* carr = (ushort*)(ws + 50*MB);         // 8 MB  [50,58)  dead after gemmC
    ushort* gy   = (ushort*)(ws + 34*MB);         // 16 MB reuse est; dead after transpose
    ushort* gyt  = (ushort*)(ws + 50*MB);         // 16 MB [50,66) reuse carr; dead after glu
    float*  mid  = (float*)(ws + 2*MB);           // 34 MB [2,36) reuse Tkb..ub (+2MB of dead gy)
    ushort* x2t  = (ushort*)(ws + 36*MB);         // 16 MB [36,52) reuse gy tail (dead) and gyt head (dead after glu)
    ushort* f1   = (ushort*)(ws + 52*MB);         // 16*G MB [52,52+16G)

    int G = (ws_size >= 117*MB) ? 4 : ((ws_size >= 85*MB) ? 2 : 1);

    k_prep_weights<<<1024, 256, 0, stream>>>(glu_w, ffn_in_w, ffn_out_w, wglu, wfi, wfo);
    k_scan_params<<<32, 256, 0, stream>>>(log_dt, log_A_real, A_imag, par);
    k_build<<<HH, 256, 0, stream>>>(log_dt, log_A_real, A_imag, C_re, C_im, Dv, Tkb, M2b, V2b);
    k_ln<2><<<BB*LL/64, 256, 0, stream>>>(x, ub, ln1_g, ln1_b);
    k_gemmA<<<BB*HH, 256, 0, stream>>>(V2b, ub, est);
    k_scan_B<<<BB*HH*NN/256, 256, 0, stream>>>(par, est, carr);
    k_gemmC<<<BB*HH, 256, 0, stream>>>(Tkb, M2b, ub, carr, gy);
    k_transpose<<<dim3(LL/64, HH/64, BB), 256, 0, stream>>>(gy, gyt);
    k_glu<<<dim3(BB*LL/128, 4), 256, 0, stream>>>(wglu, gyt, x, glu_b, mid);
    k_ln<1><<<BB*LL/64, 256, 0, stream>>>(mid, x2t, ln2_g, ln2_b);
    for (int b0 = 0; b0 < BB; b0 += G){
        int pbase = b0 * LL;
        k_gemm_lds<256,0><<<dim3(G*LL/128, 8), 256, 0, stream>>>(
            wfi, x2t + (size_t)pbase*256, ffn_in_b, nullptr, f1, 0);
        k_gemm_lds<1024,1><<<dim3(G*LL/128, 2), 256, 0, stream>>>(
            wfo, f1, ffn_out_b, mid, out, pbase);
    }
    (void)in_sizes; (void)n_in; (void)out_size; (void)ws_size;
}